// Round 1
// baseline (321.892 us; speedup 1.0000x reference)
//
#include <hip/hip_runtime.h>

#define T_STEPS 4096
#define BLOCK   256                 // 4 waves = 4 independent rows per block
#define CHUNK   8                   // elements per lane per tile
#define TILE    (64 * CHUNK)        // 512
#define NTILES  (T_STEPS / TILE)    // 8
#define RPB     (BLOCK / 64)        // rows per block

constexpr float CAP     = 13.5f;
constexpr float MAXR    = 5.0f;
constexpr float S0      = 6.75f;
constexpr float DT      = (float)(5.0 / 60.0);
constexpr float FIVE_DT = 5.0f * DT;

struct Trip { float d, l, h; };     // s -> clip(s + d, l, h)

// apply p first, then q
__device__ __forceinline__ Trip combine(const Trip& p, const Trip& q) {
    Trip r;
    r.d = p.d + q.d;
    r.l = fminf(fmaxf(p.l + q.d, q.l), q.h);
    r.h = fminf(fmaxf(p.h + q.d, q.l), q.h);
    return r;
}

__global__ __launch_bounds__(BLOCK, 4) void battery_kernel(
    const float* __restrict__ ga, const float* __restrict__ pa,
    const float* __restrict__ pp, const float* __restrict__ pr,
    float* __restrict__ trace, float* __restrict__ cost, int B)
{
    const int tid  = threadIdx.x;
    const int lane = tid & 63;
    const int wv   = tid >> 6;
    const int row  = blockIdx.x * RPB + wv;

    // per-WAVE private staging buffer, padded: element E lives at E + (E>>3)
    // (writes: addr 9*lane+j -> stride-9 = 2-way banks = free;
    //  reads:  addr lane+(lane>>3)+72m -> ~2-way = free)
    __shared__ float buf[RPB][TILE + TILE / 8];
    float* sb = buf[wv];

    if (row >= B) return;

    const long long rowOff = (long long)row * T_STEPS;
    const long long trBase = (long long)row * (T_STEPS + 1);
    const float* gaR = ga + rowOff;
    const float* paR = pa + rowOff;
    const float* ppR = pp + rowOff;
    const float* prR = pr + rowOff;

    if (lane == 0) trace[trBase] = S0;

    // prefetch tile 0 (coalesced: lane i -> 16B at i*32 .. two float4s)
    const int b0 = lane * CHUNK;
    float4 cg0 = *reinterpret_cast<const float4*>(gaR + b0);
    float4 cg1 = *reinterpret_cast<const float4*>(gaR + b0 + 4);
    float4 cp0 = *reinterpret_cast<const float4*>(paR + b0);
    float4 cp1 = *reinterpret_cast<const float4*>(paR + b0 + 4);
    float4 cq0 = *reinterpret_cast<const float4*>(ppR + b0);
    float4 cq1 = *reinterpret_cast<const float4*>(ppR + b0 + 4);
    float4 cr0 = *reinterpret_cast<const float4*>(prR + b0);
    float4 cr1 = *reinterpret_cast<const float4*>(prR + b0 + 4);

    float s = S0;   // exact row state entering the current tile

    for (int k = 0; k < NTILES; ++k) {
        // issue next tile's loads NOW: they are state-independent, so they
        // stream underneath the scan/replay chain (k==7 re-loads self, L1-hit)
        const int kn = (k + 1 < NTILES) ? k + 1 : k;
        const int nb = kn * TILE + lane * CHUNK;
        float4 ng0 = *reinterpret_cast<const float4*>(gaR + nb);
        float4 ng1 = *reinterpret_cast<const float4*>(gaR + nb + 4);
        float4 np0 = *reinterpret_cast<const float4*>(paR + nb);
        float4 np1 = *reinterpret_cast<const float4*>(paR + nb + 4);
        float4 nq0 = *reinterpret_cast<const float4*>(ppR + nb);
        float4 nq1 = *reinterpret_cast<const float4*>(ppR + nb + 4);
        float4 nr0 = *reinterpret_cast<const float4*>(prR + nb);
        float4 nr1 = *reinterpret_cast<const float4*>(prR + nb + 4);

        const float gaA[8] = {cg0.x,cg0.y,cg0.z,cg0.w,cg1.x,cg1.y,cg1.z,cg1.w};
        const float paA[8] = {cp0.x,cp0.y,cp0.z,cp0.w,cp1.x,cp1.y,cp1.z,cp1.w};
        const float ppA[8] = {cq0.x,cq0.y,cq0.z,cq0.w,cq1.x,cq1.y,cq1.z,cq1.w};
        const float prA[8] = {cr0.x,cr0.y,cr0.z,cr0.w,cr1.x,cr1.y,cr1.z,cr1.w};

        // ---- phase 1: compose this lane's 8 contiguous steps ----
        float aA[8], agrA[8];
        Trip acc;
        #pragma unroll
        for (int j = 0; j < CHUNK; ++j) {
            float rate = fminf(fmaxf(paA[j] * ppA[j], 0.0f), MAXR);
            float a    = rate * DT;                   // prov_pv_amount
            float agr  = gaA[j] * MAXR;
            float u    = agr * DT;
            aA[j] = a; agrA[j] = agr;
            Trip f;
            f.d = a + fminf(fmaxf(u, -FIVE_DT), FIVE_DT - a);
            f.l = 0.0f;
            f.h = fminf(fmaxf(CAP + u, CAP - FIVE_DT), CAP);
            acc = (j == 0) ? f : combine(acc, f);
        }

        // ---- wave-level inclusive scan (64 lanes = 512 steps) ----
        #pragma unroll
        for (int off = 1; off < 64; off <<= 1) {
            Trip p;
            p.d = __shfl_up(acc.d, off);
            p.l = __shfl_up(acc.l, off);
            p.h = __shfl_up(acc.h, off);
            if (lane >= off) acc = combine(p, acc);
        }

        // exclusive -> state entering this lane's chunk
        float exd = __shfl_up(acc.d, 1);
        float exl = __shfl_up(acc.l, 1);
        float exh = __shfl_up(acc.h, 1);
        float scur = fminf(fmaxf(s + exd, exl), exh);
        if (lane == 0) scur = s;

        // ---- phase 2: faithful reference replay ----
        float st[8], ct[8];
        #pragma unroll
        for (int j = 0; j < CHUNK; ++j) {
            float after_pv  = fminf(fmaxf(scur + aA[j], 0.0f), CAP);
            float realised  = after_pv - scur;
            float apr       = realised / DT;
            float pv_export = realised - ppA[j] * DT;
            float rgr       = fminf(fmaxf(agrA[j], -MAXR), MAXR - apr);
            float ns        = fminf(fmaxf(after_pv + rgr * DT, 0.0f), CAP);
            float grid_amt  = ns - after_pv;
            st[j] = ns;
            ct[j] = (prA[j] / 1000.0f) * (grid_amt + pv_export);
            scur  = ns;
        }
        s = __shfl(scur, 63);   // EXACT state chaining into next tile

        // cost [B,T]: aligned float4 stores (stride-32B across lanes)
        const long long cb = rowOff + (long long)k * TILE + lane * CHUNK;
        *reinterpret_cast<float4*>(cost + cb)     = make_float4(ct[0], ct[1], ct[2], ct[3]);
        *reinterpret_cast<float4*>(cost + cb + 4) = make_float4(ct[4], ct[5], ct[6], ct[7]);

        // trace [B,T+1]: +1 breaks alignment -> per-wave LDS transpose, then
        // coalesced scalar stores. Wave-private buffer: same-wave DS ops are
        // in-order, so only a compiler scheduling fence is needed (no barrier).
        #pragma unroll
        for (int j = 0; j < CHUNK; ++j)
            sb[9 * lane + j] = st[j];                 // E=8*lane+j -> E+(E>>3)=9*lane+j
        __builtin_amdgcn_wave_barrier();
        const long long tb = trBase + 1 + (long long)k * TILE;
        #pragma unroll
        for (int m = 0; m < CHUNK; ++m) {
            int E = lane + 64 * m;
            trace[tb + E] = sb[E + (E >> 3)];         // consecutive dwords across lanes
        }
        __builtin_amdgcn_wave_barrier();

        // rotate prefetch double-buffer
        cg0=ng0; cg1=ng1; cp0=np0; cp1=np1; cq0=nq0; cq1=nq1; cr0=nr0; cr1=nr1;
    }
}

extern "C" void kernel_launch(void* const* d_in, const int* in_sizes, int n_in,
                              void* d_out, int out_size, void* d_ws, size_t ws_size,
                              hipStream_t stream) {
    const float* ga = (const float*)d_in[0];   // grid_action
    const float* pa = (const float*)d_in[1];   // pv_action
    const float* pp = (const float*)d_in[2];   // pv_power
    const float* pr = (const float*)d_in[3];   // price
    const int B = in_sizes[0] / T_STEPS;
    float* trace = (float*)d_out;
    float* cost  = (float*)d_out + (long long)B * (T_STEPS + 1);
    const int grid = (B + RPB - 1) / RPB;
    battery_kernel<<<grid, BLOCK, 0, stream>>>(ga, pa, pp, pr, trace, cost, B);
}

// Round 2
// 319.008 us; speedup vs baseline: 1.0090x; 1.0090x over previous
//
#include <hip/hip_runtime.h>

#define T_STEPS 4096
#define BLOCK   256                 // 4 waves = 4 independent rows per block
#define CHUNK   8                   // elements per lane per tile
#define TILE    (64 * CHUNK)        // 512
#define NTILES  (T_STEPS / TILE)    // 8
#define RPB     (BLOCK / 64)        // rows per block

constexpr float CAP     = 13.5f;
constexpr float MAXR    = 5.0f;
constexpr float S0      = 6.75f;
constexpr float DT      = (float)(5.0 / 60.0);
constexpr float FIVE_DT = 5.0f * DT;
constexpr float INV_DT  = 1.0f / DT;      // reciprocal-mul replaces IEEE divide
constexpr float INV_1K  = 1.0f / 1000.0f; // (clip is 1-Lipschitz: 1-ulp perturbation
                                          //  cannot amplify through the state chain)

struct Trip { float d, l, h; };     // s -> clip(s + d, l, h)

// apply p first, then q
__device__ __forceinline__ Trip combine(const Trip& p, const Trip& q) {
    Trip r;
    r.d = p.d + q.d;
    r.l = fminf(fmaxf(p.l + q.d, q.l), q.h);
    r.h = fminf(fmaxf(p.h + q.d, q.l), q.h);
    return r;
}

__global__ __launch_bounds__(BLOCK, 4) void battery_kernel(
    const float* __restrict__ ga, const float* __restrict__ pa,
    const float* __restrict__ pp, const float* __restrict__ pr,
    float* __restrict__ trace, float* __restrict__ cost, int B)
{
    const int tid  = threadIdx.x;
    const int lane = tid & 63;
    const int wv   = tid >> 6;
    const int row  = blockIdx.x * RPB + wv;

    // per-WAVE private staging buffer, padded: element E lives at E + (E>>3)
    __shared__ float buf[RPB][TILE + TILE / 8];
    float* sb = buf[wv];

    if (row >= B) return;

    const long long rowOff = (long long)row * T_STEPS;
    const long long trBase = (long long)row * (T_STEPS + 1);
    const float* gaR = ga + rowOff;
    const float* paR = pa + rowOff;
    const float* ppR = pp + rowOff;
    const float* prR = pr + rowOff;

    if (lane == 0) trace[trBase] = S0;

    // prefetch tile 0 (coalesced: lane i -> two float4s at i*32)
    const int b0 = lane * CHUNK;
    float4 cg0 = *reinterpret_cast<const float4*>(gaR + b0);
    float4 cg1 = *reinterpret_cast<const float4*>(gaR + b0 + 4);
    float4 cp0 = *reinterpret_cast<const float4*>(paR + b0);
    float4 cp1 = *reinterpret_cast<const float4*>(paR + b0 + 4);
    float4 cq0 = *reinterpret_cast<const float4*>(ppR + b0);
    float4 cq1 = *reinterpret_cast<const float4*>(ppR + b0 + 4);
    float4 cr0 = *reinterpret_cast<const float4*>(prR + b0);
    float4 cr1 = *reinterpret_cast<const float4*>(prR + b0 + 4);

    float s = S0;   // exact row state entering the current tile

    for (int k = 0; k < NTILES; ++k) {
        // ---- issue next tile's loads FIRST, then FENCE so the scheduler
        // cannot sink them to their use (that sinking is what destroyed the
        // pipeline: VGPR=56 proved both buffers never coexisted). With the
        // fence, the compiler emits counted-vmcnt: wait for the 32 OLD loads
        // while the 32 NEW ones stay in flight under the tile's compute. ----
        const int kn = (k + 1 < NTILES) ? k + 1 : k;
        const int nb = kn * TILE + lane * CHUNK;
        float4 ng0 = *reinterpret_cast<const float4*>(gaR + nb);
        float4 ng1 = *reinterpret_cast<const float4*>(gaR + nb + 4);
        float4 np0 = *reinterpret_cast<const float4*>(paR + nb);
        float4 np1 = *reinterpret_cast<const float4*>(paR + nb + 4);
        float4 nq0 = *reinterpret_cast<const float4*>(ppR + nb);
        float4 nq1 = *reinterpret_cast<const float4*>(ppR + nb + 4);
        float4 nr0 = *reinterpret_cast<const float4*>(prR + nb);
        float4 nr1 = *reinterpret_cast<const float4*>(prR + nb + 4);
        __builtin_amdgcn_sched_barrier(0);   // pin prefetch above all compute

        const float gaA[8] = {cg0.x,cg0.y,cg0.z,cg0.w,cg1.x,cg1.y,cg1.z,cg1.w};
        const float paA[8] = {cp0.x,cp0.y,cp0.z,cp0.w,cp1.x,cp1.y,cp1.z,cp1.w};
        const float ppA[8] = {cq0.x,cq0.y,cq0.z,cq0.w,cq1.x,cq1.y,cq1.z,cq1.w};
        const float prA[8] = {cr0.x,cr0.y,cr0.z,cr0.w,cr1.x,cr1.y,cr1.z,cr1.w};

        // ---- phase 1: compose this lane's 8 contiguous steps ----
        float aA[8], agrA[8];
        Trip acc;
        #pragma unroll
        for (int j = 0; j < CHUNK; ++j) {
            float rate = fminf(fmaxf(paA[j] * ppA[j], 0.0f), MAXR);
            float a    = rate * DT;                   // prov_pv_amount
            float agr  = gaA[j] * MAXR;
            float u    = agr * DT;
            aA[j] = a; agrA[j] = agr;
            Trip f;
            f.d = a + fminf(fmaxf(u, -FIVE_DT), FIVE_DT - a);
            f.l = 0.0f;
            f.h = fminf(fmaxf(CAP + u, CAP - FIVE_DT), CAP);
            acc = (j == 0) ? f : combine(acc, f);
        }

        // ---- wave-level inclusive scan (64 lanes = 512 steps) ----
        #pragma unroll
        for (int off = 1; off < 64; off <<= 1) {
            Trip p;
            p.d = __shfl_up(acc.d, off);
            p.l = __shfl_up(acc.l, off);
            p.h = __shfl_up(acc.h, off);
            if (lane >= off) acc = combine(p, acc);
        }

        // exclusive -> state entering this lane's chunk
        float exd = __shfl_up(acc.d, 1);
        float exl = __shfl_up(acc.l, 1);
        float exh = __shfl_up(acc.h, 1);
        float scur = fminf(fmaxf(s + exd, exl), exh);
        if (lane == 0) scur = s;

        // ---- phase 2: faithful replay, divide-free serial chain ----
        float st[8], ct[8];
        #pragma unroll
        for (int j = 0; j < CHUNK; ++j) {
            float after_pv  = fminf(fmaxf(scur + aA[j], 0.0f), CAP);
            float realised  = after_pv - scur;
            float apr       = realised * INV_DT;      // was: realised / DT
            float pv_export = realised - ppA[j] * DT;
            float rgr       = fminf(fmaxf(agrA[j], -MAXR), MAXR - apr);
            float ns        = fminf(fmaxf(after_pv + rgr * DT, 0.0f), CAP);
            float grid_amt  = ns - after_pv;
            st[j] = ns;
            ct[j] = (prA[j] * INV_1K) * (grid_amt + pv_export);  // was: /1000
            scur  = ns;
        }
        s = __shfl(scur, 63);   // EXACT state chaining into next tile

        // cost [B,T]: aligned float4 stores
        const long long cb = rowOff + (long long)k * TILE + lane * CHUNK;
        *reinterpret_cast<float4*>(cost + cb)     = make_float4(ct[0], ct[1], ct[2], ct[3]);
        *reinterpret_cast<float4*>(cost + cb + 4) = make_float4(ct[4], ct[5], ct[6], ct[7]);

        // trace [B,T+1]: +1 breaks alignment -> per-wave LDS transpose, then
        // coalesced scalar stores (same-wave DS ops are in-order; fence only)
        #pragma unroll
        for (int j = 0; j < CHUNK; ++j)
            sb[9 * lane + j] = st[j];                 // E=8*lane+j -> 9*lane+j
        __builtin_amdgcn_wave_barrier();
        const long long tb = trBase + 1 + (long long)k * TILE;
        #pragma unroll
        for (int m = 0; m < CHUNK; ++m) {
            int E = lane + 64 * m;
            trace[tb + E] = sb[E + (E >> 3)];
        }
        __builtin_amdgcn_wave_barrier();

        // rotate prefetch double-buffer
        cg0=ng0; cg1=ng1; cp0=np0; cp1=np1; cq0=nq0; cq1=nq1; cr0=nr0; cr1=nr1;
    }
}

extern "C" void kernel_launch(void* const* d_in, const int* in_sizes, int n_in,
                              void* d_out, int out_size, void* d_ws, size_t ws_size,
                              hipStream_t stream) {
    const float* ga = (const float*)d_in[0];   // grid_action
    const float* pa = (const float*)d_in[1];   // pv_action
    const float* pp = (const float*)d_in[2];   // pv_power
    const float* pr = (const float*)d_in[3];   // price
    const int B = in_sizes[0] / T_STEPS;
    float* trace = (float*)d_out;
    float* cost  = (float*)d_out + (long long)B * (T_STEPS + 1);
    const int grid = (B + RPB - 1) / RPB;
    battery_kernel<<<grid, BLOCK, 0, stream>>>(ga, pa, pp, pr, trace, cost, B);
}